// Round 3
// baseline (159.338 us; speedup 1.0000x reference)
//
#include <hip/hip_runtime.h>
#include <math.h>

#define BB 32
#define CC 384
#define HH 56
#define WW 56
#define HWSZ (HH*WW)          // 3136
#define EPSF 1e-6f

#define TS2 84                // conv tile row stride (floats) = 21 quads; 5-quad/row bank skew
#define TR2 34                // tile rows per half-plane (28 outputs + 6 halo)
#define TILE_F (TR2*TS2)      // 2856 floats = 11424 B per wave

// ---------------- kernel 1: per-(b,c) mean + max over H*W ----------------
__global__ __launch_bounds__(256) void pool_kernel(const float* __restrict__ x,
                                                   float* __restrict__ xavg,
                                                   float* __restrict__ xmax) {
    int plane = blockIdx.x;                       // b*C + c
    const float4* xp = (const float4*)(x + (size_t)plane * HWSZ);
    int t = threadIdx.x;
    float s = 0.f, m = -INFINITY;
    for (int i = t; i < HWSZ/4; i += 256) {       // 784 float4
        float4 v = xp[i];
        s += v.x + v.y + v.z + v.w;
        m = fmaxf(m, fmaxf(fmaxf(v.x, v.y), fmaxf(v.z, v.w)));
    }
    for (int off = 32; off; off >>= 1) {
        s += __shfl_down(s, off, 64);
        m = fmaxf(m, __shfl_down(m, off, 64));
    }
    __shared__ float ss[4], sm[4];
    int wid = t >> 6;
    if ((t & 63) == 0) { ss[wid] = s; sm[wid] = m; }
    __syncthreads();
    if (t == 0) {
        s = ss[0] + ss[1] + ss[2] + ss[3];
        m = fmaxf(fmaxf(sm[0], sm[1]), fmaxf(sm[2], sm[3]));
        xavg[plane] = s * (1.0f / HWSZ);
        xmax[plane] = m;
    }
}

// ---------------- kernel 2: GEMVs + GELU + FGRN -> per-sample 7x7 kernels ----------------
__global__ __launch_bounds__(384) void weights_kernel(
        const float* __restrict__ xavg, const float* __restrict__ xmax,
        const float* __restrict__ w_avg, const float* __restrict__ b_avg,
        const float* __restrict__ w_max, const float* __restrict__ b_max,
        const float* __restrict__ w_mix, const float* __restrict__ gamma,
        const float* __restrict__ beta, float* __restrict__ kern) {
    int b = blockIdx.x, c = threadIdx.x;
    __shared__ float xa[CC], xm[CC], red[512];
    xa[c] = xavg[b*CC + c];
    xm[c] = xmax[b*CC + c];
    if (c < 512 - CC) red[CC + c] = 0.f;
    __syncthreads();

    const float4* wa = (const float4*)(w_avg + (size_t)c * CC);
    const float4* wm = (const float4*)(w_max + (size_t)c * CC);
    float acc = b_avg[c] + b_max[c];
    #pragma unroll 4
    for (int q = 0; q < CC/4; ++q) {
        float4 a4 = wa[q], m4 = wm[q];
        const float* xap = &xa[q*4];
        const float* xmp = &xm[q*4];
        acc += a4.x*xap[0] + a4.y*xap[1] + a4.z*xap[2] + a4.w*xap[3];
        acc += m4.x*xmp[0] + m4.y*xmp[1] + m4.z*xmp[2] + m4.w*xmp[3];
    }
    float xw = 0.5f * acc * (1.0f + erff(acc * 0.70710678118654752f));

    float wrow[49];
    float sq = 0.f;
    const float* wmx = w_mix + c*49;
    #pragma unroll
    for (int j = 0; j < 49; ++j) { wrow[j] = wmx[j]; sq += wrow[j]*wrow[j]; }
    float Gx = fabsf(xw) * sqrtf(sq);

    red[c] = Gx;
    __syncthreads();
    for (int off = 256; off > 0; off >>= 1) {
        if (c < off) red[c] += red[c + off];
        __syncthreads();
    }
    float meanG = red[0] * (1.0f / CC);
    float Nx = Gx / (meanG + EPSF);

    float g = gamma[c], bt = beta[c];
    float coef = g * xw * Nx;
    float* kp = kern + ((size_t)(b*CC + c)) * 49;
    #pragma unroll
    for (int j = 0; j < 49; ++j) kp[j] = coef * wrow[j] + bt;
}

// ---------------- kernel 3: dynamic depthwise 7x7 conv ----------------
// 4 waves/block, each wave owns one (b,c) plane; NO block barriers.
// Plane processed as 2 half-tiles of 28 output rows (+3 halo each side).
// Lane (s,g): 4-wide x 7-tall output patch, rows [28h+7g, +7), cols [4s, +4).
__global__ __launch_bounds__(256, 3) void conv_kernel(const float* __restrict__ x,
                                                      const float* __restrict__ kern,
                                                      float* __restrict__ out) {
    int t = threadIdx.x;
    int wave = t >> 6;
    int lane = t & 63;
    int plane = blockIdx.x * 4 + wave;
    const float4* xp4 = (const float4*)(x + (size_t)plane * HWSZ);
    float4* op4 = (float4*)(out + (size_t)plane * HWSZ);

    __shared__ float lds[4 * TILE_F];    // 45696 B
    float* tile = &lds[wave * TILE_F];

    // kernel taps -> wave-uniform SGPRs
    float kfv[49];
    {
        const float* kp = kern + (size_t)plane * 49;
        #pragma unroll
        for (int j = 0; j < 49; ++j) {
            union { float f; int i; } u;
            u.f = kp[j];
            u.i = __builtin_amdgcn_readfirstlane(u.i);
            kfv[j] = u.f;
        }
    }

    int s = lane & 15;
    int g = lane >> 4;                   // 0..3
    bool active = (s < 14);
    int sc = active ? s : 0;

    float4 z4 = make_float4(0.f, 0.f, 0.f, 0.f);

    #pragma unroll 1
    for (int h = 0; h < 2; ++h) {
        // WAR: previous half's reads must drain before tile is overwritten
        asm volatile("s_waitcnt lgkmcnt(0)" ::: "memory");

        // zero side quads (quad 0: cols 0..3, quad 15: cols 60..63) for all 34 rows
        for (int i = lane; i < 68; i += 64) {
            int r = (i < 34) ? i : (i - 34);
            int q = (i < 34) ? 0 : 15;
            *(float4*)&tile[r*TS2 + q*4] = z4;
        }
        // zero 3 halo rows x quads 0..15 (h=0: tile rows 0..2; h=1: rows 31..33)
        if (lane < 48) {
            int r = (h == 0) ? (lane >> 4) : (31 + (lane >> 4));
            int q = lane & 15;
            *(float4*)&tile[r*TS2 + q*4] = z4;
        }
        // stage 31 input rows x 14 quads: input row r_lo+rr -> tile row rr+tr_off
        int r_lo   = (h == 0) ? 0 : 25;
        int tr_off = (h == 0) ? 3 : 0;
        for (int i = lane; i < 31*14; i += 64) {
            int rr = i / 14;
            int qq = i - rr*14;
            float4 v = xp4[(r_lo + rr)*14 + qq];
            *(float4*)&tile[(rr + tr_off)*TS2 + (qq + 1)*4] = v;
        }
        asm volatile("s_waitcnt lgkmcnt(0)" ::: "memory");

        float acc[7][4];
        #pragma unroll
        for (int i = 0; i < 7; ++i)
            #pragma unroll
            for (int j = 0; j < 4; ++j) acc[i][j] = 0.f;

        // tile rows 7g+ry, ry=0..12; out(7g+oy, 4sc+j) sums k[ky][kx]*tile[7g+oy+ky][4sc+j+kx+1]
        #pragma unroll
        for (int ry = 0; ry < 13; ++ry) {
            const float* rp = &tile[(7*g + ry)*TS2 + sc*4];
            float rv[12];
            #pragma unroll
            for (int q = 0; q < 3; ++q)
                *(float4*)&rv[q*4] = *(const float4*)&rp[q*4];

            int oy_lo = (ry - 6 > 0) ? (ry - 6) : 0;
            int oy_hi = (ry < 6) ? ry : 6;
            #pragma unroll
            for (int oy = 0; oy < 7; ++oy) {
                if (oy < oy_lo || oy > oy_hi) continue;
                int ky = ry - oy;
                #pragma unroll
                for (int kx = 0; kx < 7; ++kx) {
                    float kv = kfv[ky*7 + kx];
                    #pragma unroll
                    for (int j = 0; j < 4; ++j)
                        acc[oy][j] = fmaf(kv, rv[j + 1 + kx], acc[oy][j]);
                }
            }
        }

        if (active) {
            #pragma unroll
            for (int oy = 0; oy < 7; ++oy) {
                int orow = h*28 + 7*g + oy;
                float4 o; o.x = acc[oy][0]; o.y = acc[oy][1]; o.z = acc[oy][2]; o.w = acc[oy][3];
                op4[orow*14 + sc] = o;
            }
        }
    }
}

extern "C" void kernel_launch(void* const* d_in, const int* in_sizes, int n_in,
                              void* d_out, int out_size, void* d_ws, size_t ws_size,
                              hipStream_t stream) {
    const float* x     = (const float*)d_in[0];
    const float* w_avg = (const float*)d_in[1];
    const float* b_avg = (const float*)d_in[2];
    const float* w_max = (const float*)d_in[3];
    const float* b_max = (const float*)d_in[4];
    const float* w_mix = (const float*)d_in[5];
    const float* gamma = (const float*)d_in[6];
    const float* beta  = (const float*)d_in[7];
    float* out = (float*)d_out;

    float* ws   = (float*)d_ws;
    float* xavg = ws;                       // B*C
    float* xmax = ws + BB*CC;               // B*C
    float* kern = ws + 2*BB*CC;             // B*C*49

    pool_kernel<<<BB*CC, 256, 0, stream>>>(x, xavg, xmax);
    weights_kernel<<<BB, CC, 0, stream>>>(xavg, xmax, w_avg, b_avg, w_max, b_max,
                                          w_mix, gamma, beta, kern);
    conv_kernel<<<BB*CC/4, 256, 0, stream>>>(x, kern, out);
}